// Round 4
// baseline (974.519 us; speedup 1.0000x reference)
//
#include <hip/hip_runtime.h>
#include <hip/hip_bf16.h>
#include <stdint.h>

// Problem constants (from reference setup_inputs)
#define N_NODES 50000
#define NE      400000
#define HDIM    128
#define MPAD    50048     // 391 * 128, zero-padded rows for clean GEMM tiling
#define TE      128       // edges per block in edge kernel

typedef __attribute__((ext_vector_type(8))) short bf16x8;   // 8 bf16 in 4 VGPRs
typedef __attribute__((ext_vector_type(4))) float f32x4;

__device__ __forceinline__ ushort f2b(float f) {
    uint32_t u = __float_as_uint(f);
    uint32_t r = (u + 0x7fffu + ((u >> 16) & 1u)) >> 16;   // RTNE
    return (ushort)r;
}
__device__ __forceinline__ float b2f(ushort s) {
    return __uint_as_float(((uint32_t)s) << 16);
}
__device__ __forceinline__ float silu_f(float x) {
    return x / (1.f + __expf(-x));
}
__device__ __forceinline__ float tanh_f(float x) {
    return 1.f - 2.f / (__expf(2.f * x) + 1.f);
}

// async global->LDS 16B deposit: per-lane global addr, wave-uniform LDS base,
// HW writes ldsbase + lane*16.  Zero VGPR result cost -> deep MLP via vmcnt.
__device__ __forceinline__ void gload_lds16(const void* gp, void* lp) {
    __builtin_amdgcn_global_load_lds(
        (const __attribute__((address_space(1))) void*)gp,
        (__attribute__((address_space(3))) void*)lp, 16, 0, 0);
}

// ---------------------------------------------------------------------------
// Fused: Xc[row,0:128]=bf16(x), Xc[row,128:256]=bf16(pe) (pad rows 0),
// and out[0:NH)=x, out[NH:2NH)=pe (baseline for deg-0 nodes / boundary atomics).
__global__ void k_prep_nodes(const float4* __restrict__ x, const float4* __restrict__ pe,
                             ushort* __restrict__ Xc, float4* __restrict__ out) {
    int idx = blockIdx.x * 256 + threadIdx.x;   // MPAD*64 tasks (4 floats each)
    int row = idx >> 6;
    int cq  = idx & 63;
    float4 v = make_float4(0.f, 0.f, 0.f, 0.f);
    if (row < N_NODES) {
        if (cq < 32) { v = x[row * 32 + cq];          out[row * 32 + cq] = v; }
        else         { v = pe[row * 32 + (cq - 32)];  out[N_NODES * 32 + row * 32 + (cq - 32)] = v; }
    }
    ushort r[4] = { f2b(v.x), f2b(v.y), f2b(v.z), f2b(v.w) };
    *(uint2*)(Xc + (size_t)row * 256 + cq * 4) = *(const uint2*)r;
}

// Build transposed bf16 weights + dist-row extracts.
__global__ void k_prep_w(const float* __restrict__ W1, const float* __restrict__ Wp1,
                         const float* __restrict__ W2, const float* __restrict__ Wp2,
                         ushort* __restrict__ WcT, ushort* __restrict__ W2t,
                         ushort* __restrict__ Wp2t, float* __restrict__ w1d,
                         float* __restrict__ wp1d) {
    int b = blockIdx.x, t = threadIdx.x;
    if (b < 512) {
        int n = b, k = t;
        float v;
        if (n < 128)       v = W1[k * HDIM + n];
        else if (n < 256)  v = W1[(256 + k) * HDIM + (n - 128)];
        else if (n < 384)  v = (k < 128) ? 0.f : Wp1[(k - 128) * HDIM + (n - 256)];
        else               v = (k < 128) ? 0.f : Wp1[k * HDIM + (n - 384)];
        WcT[n * 256 + k] = f2b(v);
    } else if (b < 640) {
        if (t < 128) { int n = b - 512; W2t[n * HDIM + t] = f2b(W2[t * HDIM + n]); }
    } else if (b < 768) {
        if (t < 128) { int n = b - 640; Wp2t[n * HDIM + t] = f2b(Wp2[t * HDIM + n]); }
    } else {
        if (t < 128) w1d[t] = W1[512 * HDIM + t];
        else if (t < 256) wp1d[t - 128] = Wp1[256 * HDIM + (t - 128)];
    }
}

// ---------------------------------------------------------------------------
// Counting sort of edges by receiver node.
__global__ void k_hist(const int* __restrict__ eidx, int* __restrict__ cnt) {
    int e = blockIdx.x * 256 + threadIdx.x;
    if (e < NE) atomicAdd(&cnt[eidx[NE + e]], 1);
}

__global__ __launch_bounds__(1024) void k_scan(const int* __restrict__ cnt,
                                               int* __restrict__ start,
                                               int* __restrict__ cursor) {
    __shared__ int part[1024];
    const int CH = 49;                       // 1024*49 = 50176 >= 50000
    int tid = threadIdx.x;
    int lo = tid * CH, hi = min(lo + CH, N_NODES);
    int s = 0;
    for (int i = lo; i < hi; i++) s += cnt[i];
    part[tid] = s;
    __syncthreads();
    for (int off = 1; off < 1024; off <<= 1) {
        int v = (tid >= off) ? part[tid - off] : 0;
        __syncthreads();
        part[tid] += v;
        __syncthreads();
    }
    int run = tid ? part[tid - 1] : 0;
    for (int i = lo; i < hi; i++) {
        start[i] = run; cursor[i] = run;
        run += cnt[i];
    }
    if (tid == 1023) start[N_NODES] = part[1023];
}

__global__ void k_place(const int* __restrict__ eidx, int* __restrict__ cursor,
                        int* __restrict__ perm) {
    int e = blockIdx.x * 256 + threadIdx.x;
    if (e < NE) {
        int p = atomicAdd(&cursor[eidx[NE + e]], 1);
        perm[p] = e;
    }
}

// ---------------------------------------------------------------------------
// Pn[MPAD,512] bf16 = Xc[MPAD,256] @ Wc[256,512], via WcT.
__global__ __launch_bounds__(256) void k_node_gemm(const ushort* __restrict__ Xc,
                                                   const ushort* __restrict__ WcT,
                                                   ushort* __restrict__ Pn) {
    const int m0 = blockIdx.y * 128;
    const int n0 = blockIdx.x * 128;
    const int wave = threadIdx.x >> 6;
    const int lane = threadIdx.x & 63;
    const int l15 = lane & 15, quad = lane >> 4;
    const int qr = (wave >> 1) * 64, qc = (wave & 1) * 64;

    f32x4 acc[4][4];
#pragma unroll
    for (int i = 0; i < 4; i++)
#pragma unroll
        for (int j = 0; j < 4; j++) acc[i][j] = (f32x4){0.f, 0.f, 0.f, 0.f};

#pragma unroll
    for (int s = 0; s < 8; s++) {
        const int k0 = s * 32 + quad * 8;
        bf16x8 a[4], b[4];
#pragma unroll
        for (int rg = 0; rg < 4; rg++) {
            int row = m0 + qr + rg * 16 + l15;
            a[rg] = *(const bf16x8*)(Xc + row * 256 + k0);
        }
#pragma unroll
        for (int cg = 0; cg < 4; cg++) {
            int nn = n0 + qc + cg * 16 + l15;
            b[cg] = *(const bf16x8*)(WcT + nn * 256 + k0);
        }
#pragma unroll
        for (int rg = 0; rg < 4; rg++)
#pragma unroll
            for (int cg = 0; cg < 4; cg++)
                acc[rg][cg] = __builtin_amdgcn_mfma_f32_16x16x32_bf16(a[rg], b[cg], acc[rg][cg], 0, 0, 0);
    }

#pragma unroll
    for (int rg = 0; rg < 4; rg++)
#pragma unroll
        for (int cg = 0; cg < 4; cg++) {
            int col = n0 + qc + cg * 16 + l15;
            int rowb = m0 + qr + rg * 16 + quad * 4;
#pragma unroll
            for (int r = 0; r < 4; r++)
                Pn[(size_t)(rowb + r) * 512 + col] = f2b(acc[rg][cg][r]);
        }
}

// ---------------------------------------------------------------------------
// Edge kernel v4: one block = 128 rec-sorted edges, BOTH paths sequentially.
// Send-half gathers via async global_load_lds (deep MLP, no VGPR cost);
// rec-half via normal loads (rec-sorted -> L1 hits).  h1 tile XOR-chunk
// swizzled so unpadded 256B rows stay conflict-free for ds_read_b128.
__global__ __launch_bounds__(256, 2) void k_edge(
    const ushort* __restrict__ Pn, const float* __restrict__ pos,
    const int* __restrict__ eidx, const int* __restrict__ perm,
    const int* __restrict__ startA, const int* __restrict__ cntA,
    const float* __restrict__ x, const float* __restrict__ pe,
    const float* __restrict__ w1d, const float* __restrict__ b1,
    const ushort* __restrict__ W2t, const float* __restrict__ b2,
    const float* __restrict__ wp1d, const float* __restrict__ bp1,
    const ushort* __restrict__ Wp2t, const float* __restrict__ bp2,
    float* __restrict__ out)
{
    __shared__ __align__(16) ushort sU[TE * 128];   // send-half raw tile (32 KB), lds-load layout
    __shared__ __align__(16) ushort sH[TE * 128];   // h1 (swizzled) then msg tile (32 KB)
    __shared__ float sDist[TE];
    __shared__ int sSend[TE], sRec[TE];
    __shared__ int sFlag[TE];
    __shared__ int sSegStart[TE + 1];

    const int tid = threadIdx.x;
    const int e0 = blockIdx.x * TE;

    if (tid < TE) {
        int e = perm[e0 + tid];
        int s = eidx[e], r = eidx[NE + e];
        float dx = pos[s * 3 + 0] - pos[r * 3 + 0];
        float dy = pos[s * 3 + 1] - pos[r * 3 + 1];
        float dz = pos[s * 3 + 2] - pos[r * 3 + 2];
        sDist[tid] = sqrtf(dx * dx + dy * dy + dz * dz);
        sSend[tid] = s; sRec[tid] = r;
    }
    __syncthreads();

    // segment-start flags + inclusive scan -> segment boundaries (done once)
    if (tid < TE) sFlag[tid] = (tid == 0) || (sRec[tid] != sRec[tid - 1]);
    __syncthreads();
    for (int off = 1; off < TE; off <<= 1) {
        int v = (tid < TE && tid >= off) ? sFlag[tid - off] : 0;
        __syncthreads();
        if (tid < TE) sFlag[tid] += v;
        __syncthreads();
    }
    if (tid < TE && (tid == 0 || sFlag[tid] != sFlag[tid - 1]))
        sSegStart[sFlag[tid] - 1] = tid;
    if (tid == 0) sSegStart[sFlag[TE - 1]] = TE;
    __syncthreads();
    const int nSeg = sFlag[TE - 1];

    const int wave = tid >> 6, lane = tid & 63;
    const int l15 = lane & 15, quad = lane >> 4;

    for (int p = 0; p < 2; p++) {
        const ushort* Wt = p ? Wp2t : W2t;
        const float* wd  = p ? wp1d : w1d;
        const float* bb1 = p ? bp1  : b1;
        const float* bb2 = p ? bp2  : b2;
        const float* basep = p ? pe : x;

        // ---- phase 1: async gather of send halves into sU ----
        // wave issues 8 lds-loads; each covers 64 lanes x 16B = 4 edges x 256B.
#pragma unroll
        for (int t = 0; t < 8; t++) {
            int instr = wave * 8 + t;                 // 0..31
            int e = instr * 4 + (lane >> 4);
            int c = lane & 15;
            const ushort* gp = Pn + (size_t)sSend[e] * 512 + p * 256 + c * 8;
            gload_lds16(gp, &sU[instr * 512]);        // uniform LDS base per instr
        }
        __syncthreads();   // compiler drains vmcnt here -> sU complete

        // ---- phase 2: layer 1 + activation -> swizzled h1 tile ----
        for (int i = tid; i < TE * 16; i += 256) {
            int e = i >> 4, c = i & 15;
            float d = sDist[e];
            uint4 us = *(const uint4*)&sU[e * 128 + c * 8];
            uint4 ur = *(const uint4*)(Pn + (size_t)sRec[e] * 512 + p * 256 + 128 + c * 8);
            const ushort* pus = (const ushort*)&us;
            const ushort* pur = (const ushort*)&ur;
            ushort res[8];
#pragma unroll
            for (int j = 0; j < 8; j++) {
                int ch = c * 8 + j;
                float v = b2f(pus[j]) + b2f(pur[j]) + d * wd[ch] + bb1[ch];
                v = p ? tanh_f(v) : silu_f(v);
                res[j] = f2b(v);
            }
            *(uint4*)&sH[e * 128 + ((c ^ (e & 15)) * 8)] = *(const uint4*)res;
        }
        __syncthreads();

        // ---- phase 3: MFMA layer 2 (A from swizzled sH, B from global/L1) ----
        f32x4 acc[2][8];
#pragma unroll
        for (int rg = 0; rg < 2; rg++)
#pragma unroll
            for (int cg = 0; cg < 8; cg++) acc[rg][cg] = (f32x4){0.f, 0.f, 0.f, 0.f};

#pragma unroll
        for (int s4 = 0; s4 < 4; s4++) {
            int cidx = s4 * 4 + quad;                 // logical chunk
            int row0 = wave * 32 + l15;
            int row1 = row0 + 16;
            bf16x8 a0 = *(const bf16x8*)&sH[row0 * 128 + ((cidx ^ l15) * 8)];
            bf16x8 a1 = *(const bf16x8*)&sH[row1 * 128 + ((cidx ^ l15) * 8)];
            int k0 = cidx * 8;
#pragma unroll
            for (int cg = 0; cg < 8; cg++) {
                bf16x8 b = *(const bf16x8*)(Wt + (cg * 16 + l15) * HDIM + k0);
                acc[0][cg] = __builtin_amdgcn_mfma_f32_16x16x32_bf16(a0, b, acc[0][cg], 0, 0, 0);
                acc[1][cg] = __builtin_amdgcn_mfma_f32_16x16x32_bf16(a1, b, acc[1][cg], 0, 0, 0);
            }
        }
        __syncthreads();   // all h1 reads complete before msg overwrite

        // ---- phase 4: bias + act, msg tile into sH (plain layout) ----
#pragma unroll
        for (int rg = 0; rg < 2; rg++) {
            int rowb = wave * 32 + rg * 16 + quad * 4;
#pragma unroll
            for (int cg = 0; cg < 8; cg++) {
                int col = cg * 16 + l15;
                float bias = bb2[col];
#pragma unroll
                for (int r = 0; r < 4; r++) {
                    float v = acc[rg][cg][r] + bias;
                    v = p ? tanh_f(v) : silu_f(v);
                    sH[(rowb + r) * 128 + col] = f2b(v);
                }
            }
        }
        __syncthreads();

        // ---- phase 5: segment reduce + store/atomic ----
        float* outb = out + (size_t)p * N_NODES * HDIM;
        for (int task = tid; task < nSeg * 64; task += 256) {
            int seg = task >> 6, cp = task & 63;
            int r0 = sSegStart[seg], r1 = sSegStart[seg + 1];
            float a0 = 0.f, a1 = 0.f;
            for (int rr = r0; rr < r1; rr++) {
                unsigned int u = *(const unsigned int*)&sH[rr * 128 + cp * 2];
                a0 += b2f((ushort)(u & 0xffffu));
                a1 += b2f((ushort)(u >> 16));
            }
            int n = sRec[r0];
            int g0 = e0 + r0;
            bool interior = (g0 == startA[n]) && (g0 + (r1 - r0) == startA[n] + cntA[n]);
            float* op = outb + (size_t)n * HDIM + cp * 2;
            if (interior) {
                float2 bv = *(const float2*)(basep + (size_t)n * HDIM + cp * 2);
                *(float2*)op = make_float2(bv.x + a0, bv.y + a1);
            } else {
                atomicAdd(op, a0);
                atomicAdd(op + 1, a1);
            }
        }
        __syncthreads();   // sU/sH reused by next path
    }
}

// ---------------------------------------------------------------------------
extern "C" void kernel_launch(void* const* d_in, const int* in_sizes, int n_in,
                              void* d_out, int out_size, void* d_ws, size_t ws_size,
                              hipStream_t stream) {
    const float* x   = (const float*)d_in[0];
    const float* pos = (const float*)d_in[1];
    const float* pe  = (const float*)d_in[2];
    const int* eidx  = (const int*)d_in[3];
    const float* W1  = (const float*)d_in[4];
    const float* b1  = (const float*)d_in[5];
    const float* W2  = (const float*)d_in[6];
    const float* b2  = (const float*)d_in[7];
    const float* Wp1 = (const float*)d_in[8];
    const float* bp1 = (const float*)d_in[9];
    const float* Wp2 = (const float*)d_in[10];
    const float* bp2 = (const float*)d_in[11];
    float* out = (float*)d_out;

    // workspace carve-up
    char* w = (char*)d_ws;
    size_t off = 0;
    ushort* Xc   = (ushort*)(w + off); off += (size_t)MPAD * 256 * 2;
    ushort* Pn   = (ushort*)(w + off); off += (size_t)MPAD * 512 * 2;
    ushort* WcT  = (ushort*)(w + off); off += 512 * 256 * 2;
    ushort* W2t  = (ushort*)(w + off); off += 32768;
    ushort* Wp2t = (ushort*)(w + off); off += 32768;
    float*  w1d  = (float*)(w + off);  off += 2048;
    float*  wp1d = (float*)(w + off);  off += 2048;
    int* cnt     = (int*)(w + off);    off += 200704;
    int* startA  = (int*)(w + off);    off += 200704;
    int* cursor  = (int*)(w + off);    off += 200704;
    int* perm    = (int*)(w + off);    off += (size_t)NE * 4;

    // sort edges by receiver
    hipMemsetAsync(cnt, 0, (N_NODES + 1) * sizeof(int), stream);
    k_hist<<<(NE + 255) / 256, 256, 0, stream>>>(eidx, cnt);
    k_scan<<<1, 1024, 0, stream>>>(cnt, startA, cursor);
    k_place<<<(NE + 255) / 256, 256, 0, stream>>>(eidx, cursor, perm);

    // prep (fused Xc build + out baseline init)
    k_prep_w<<<769, 256, 0, stream>>>(W1, Wp1, W2, Wp2, WcT, W2t, Wp2t, w1d, wp1d);
    k_prep_nodes<<<MPAD / 4, 256, 0, stream>>>((const float4*)x, (const float4*)pe,
                                               Xc, (float4*)out);

    // node-level GEMM: Pn = Xc @ Wc
    dim3 ggrid(4, MPAD / 128);
    k_node_gemm<<<ggrid, 256, 0, stream>>>(Xc, WcT, Pn);

    // edge pipeline: sorted edges, async send-gather, in-block segment reduce
    k_edge<<<NE / TE, 256, 0, stream>>>(Pn, pos, eidx, perm, startA, cnt, x, pe,
                                        w1d, b1, W2t, b2, wp1d, bp1, Wp2t, bp2, out);
}

// Round 5
// 499.655 us; speedup vs baseline: 1.9504x; 1.9504x over previous
//
#include <hip/hip_runtime.h>
#include <hip/hip_bf16.h>
#include <stdint.h>

// Problem constants (from reference setup_inputs)
#define N_NODES 50000
#define NE      400000
#define HDIM    128
#define MPAD    50048     // 391 * 128, zero-padded rows for clean GEMM tiling
#define TE      128       // edges per tile in gemm kernel
#define SCAN_BS 512
#define SCAN_NB 98        // 98*512 = 50176 >= 50001

typedef __attribute__((ext_vector_type(8))) short bf16x8;   // 8 bf16 in 4 VGPRs
typedef __attribute__((ext_vector_type(4))) float f32x4;

__device__ __forceinline__ ushort f2b(float f) {
    uint32_t u = __float_as_uint(f);
    uint32_t r = (u + 0x7fffu + ((u >> 16) & 1u)) >> 16;   // RTNE
    return (ushort)r;
}
__device__ __forceinline__ float b2f(ushort s) {
    return __uint_as_float(((uint32_t)s) << 16);
}
__device__ __forceinline__ float silu_f(float x) {
    return x / (1.f + __expf(-x));
}
__device__ __forceinline__ float tanh_f(float x) {
    return 1.f - 2.f / (__expf(2.f * x) + 1.f);
}

// async global->LDS 16B: per-lane global addr, deposit at ldsbase + lane*16
__device__ __forceinline__ void gload_lds16(const void* gp, void* lp) {
    __builtin_amdgcn_global_load_lds(
        (const __attribute__((address_space(1))) void*)gp,
        (__attribute__((address_space(3))) void*)lp, 16, 0, 0);
}

// ---------------------------------------------------------------------------
// Fused: Xc[row,0:128]=bf16(x), Xc[row,128:256]=bf16(pe) (pad rows 0),
// and out[0:NH)=x, out[NH:2NH)=pe (baseline for deg-0 nodes / boundary atomics).
__global__ void k_prep_nodes(const float4* __restrict__ x, const float4* __restrict__ pe,
                             ushort* __restrict__ Xc, float4* __restrict__ out) {
    int idx = blockIdx.x * 256 + threadIdx.x;
    int row = idx >> 6;
    int cq  = idx & 63;
    float4 v = make_float4(0.f, 0.f, 0.f, 0.f);
    if (row < N_NODES) {
        if (cq < 32) { v = x[row * 32 + cq];          out[row * 32 + cq] = v; }
        else         { v = pe[row * 32 + (cq - 32)];  out[N_NODES * 32 + row * 32 + (cq - 32)] = v; }
    }
    ushort r[4] = { f2b(v.x), f2b(v.y), f2b(v.z), f2b(v.w) };
    *(uint2*)(Xc + (size_t)row * 256 + cq * 4) = *(const uint2*)r;
}

// Build transposed bf16 weights + dist-row extracts.
__global__ void k_prep_w(const float* __restrict__ W1, const float* __restrict__ Wp1,
                         const float* __restrict__ W2, const float* __restrict__ Wp2,
                         ushort* __restrict__ WcT, ushort* __restrict__ W2t,
                         ushort* __restrict__ Wp2t, float* __restrict__ w1d,
                         float* __restrict__ wp1d) {
    int b = blockIdx.x, t = threadIdx.x;
    if (b < 512) {
        int n = b, k = t;
        float v;
        if (n < 128)       v = W1[k * HDIM + n];
        else if (n < 256)  v = W1[(256 + k) * HDIM + (n - 128)];
        else if (n < 384)  v = (k < 128) ? 0.f : Wp1[(k - 128) * HDIM + (n - 256)];
        else               v = (k < 128) ? 0.f : Wp1[k * HDIM + (n - 384)];
        WcT[n * 256 + k] = f2b(v);
    } else if (b < 640) {
        if (t < 128) { int n = b - 512; W2t[n * HDIM + t] = f2b(W2[t * HDIM + n]); }
    } else if (b < 768) {
        if (t < 128) { int n = b - 640; Wp2t[n * HDIM + t] = f2b(Wp2[t * HDIM + n]); }
    } else {
        if (t < 128) w1d[t] = W1[512 * HDIM + t];
        else if (t < 256) wp1d[t - 128] = Wp1[256 * HDIM + (t - 128)];
    }
}

// ---------------------------------------------------------------------------
// Counting sort by receiver: hist -> 3-kernel multi-block scan -> place(+dist).
__global__ void k_hist(const int* __restrict__ eidx, int* __restrict__ cnt) {
    int e = blockIdx.x * 256 + threadIdx.x;
    if (e < NE) atomicAdd(&cnt[eidx[NE + e]], 1);
}

__global__ __launch_bounds__(SCAN_BS) void k_scan1(const int* __restrict__ cnt,
                                                   int* __restrict__ locs,
                                                   int* __restrict__ sums) {
    __shared__ int sh[SCAN_BS];
    int tid = threadIdx.x;
    int i = blockIdx.x * SCAN_BS + tid;
    int v = (i < N_NODES) ? cnt[i] : 0;
    sh[tid] = v;
    __syncthreads();
    for (int off = 1; off < SCAN_BS; off <<= 1) {
        int t = (tid >= off) ? sh[tid - off] : 0;
        __syncthreads();
        sh[tid] += t;
        __syncthreads();
    }
    locs[i] = sh[tid];                       // inclusive scan within block
    if (tid == SCAN_BS - 1) sums[blockIdx.x] = sh[tid];
}

__global__ void k_scan2(int* __restrict__ sums) {
    __shared__ int sh[128];
    int tid = threadIdx.x;
    sh[tid] = (tid < SCAN_NB) ? sums[tid] : 0;
    __syncthreads();
    for (int off = 1; off < 128; off <<= 1) {
        int t = (tid >= off) ? sh[tid - off] : 0;
        __syncthreads();
        sh[tid] += t;
        __syncthreads();
    }
    if (tid < SCAN_NB) sums[tid] = sh[tid];  // inclusive block sums
}

__global__ __launch_bounds__(SCAN_BS) void k_scan3(const int* __restrict__ cnt,
                                                   const int* __restrict__ locs,
                                                   const int* __restrict__ sums,
                                                   int* __restrict__ start,
                                                   int* __restrict__ cursor) {
    int tid = threadIdx.x, b = blockIdx.x;
    int i = b * SCAN_BS + tid;
    if (i > N_NODES) return;
    int base = b ? sums[b - 1] : 0;
    int v = (i < N_NODES) ? cnt[i] : 0;
    int ex = base + locs[i] - v;             // exclusive prefix
    start[i] = ex;
    if (i < N_NODES) cursor[i] = ex;
}

// place edge into sorted slot; also extract send/rec/dist into sorted arrays
__global__ void k_place(const int* __restrict__ eidx, const float* __restrict__ pos,
                        int* __restrict__ cursor, int* __restrict__ sendS,
                        int* __restrict__ recS, float* __restrict__ distS) {
    int e = blockIdx.x * 256 + threadIdx.x;
    if (e >= NE) return;
    int s = eidx[e], r = eidx[NE + e];
    int p = atomicAdd(&cursor[r], 1);
    sendS[p] = s; recS[p] = r;
    float dx = pos[s * 3 + 0] - pos[r * 3 + 0];
    float dy = pos[s * 3 + 1] - pos[r * 3 + 1];
    float dz = pos[s * 3 + 2] - pos[r * 3 + 2];
    distS[p] = sqrtf(dx * dx + dy * dy + dz * dz);
}

// ---------------------------------------------------------------------------
// Pn[MPAD,512] bf16 = Xc[MPAD,256] @ Wc[256,512], via WcT.
__global__ __launch_bounds__(256) void k_node_gemm(const ushort* __restrict__ Xc,
                                                   const ushort* __restrict__ WcT,
                                                   ushort* __restrict__ Pn) {
    const int m0 = blockIdx.y * 128;
    const int n0 = blockIdx.x * 128;
    const int wave = threadIdx.x >> 6;
    const int lane = threadIdx.x & 63;
    const int l15 = lane & 15, quad = lane >> 4;
    const int qr = (wave >> 1) * 64, qc = (wave & 1) * 64;

    f32x4 acc[4][4];
#pragma unroll
    for (int i = 0; i < 4; i++)
#pragma unroll
        for (int j = 0; j < 4; j++) acc[i][j] = (f32x4){0.f, 0.f, 0.f, 0.f};

#pragma unroll
    for (int s = 0; s < 8; s++) {
        const int k0 = s * 32 + quad * 8;
        bf16x8 a[4], b[4];
#pragma unroll
        for (int rg = 0; rg < 4; rg++) {
            int row = m0 + qr + rg * 16 + l15;
            a[rg] = *(const bf16x8*)(Xc + row * 256 + k0);
        }
#pragma unroll
        for (int cg = 0; cg < 4; cg++) {
            int nn = n0 + qc + cg * 16 + l15;
            b[cg] = *(const bf16x8*)(WcT + nn * 256 + k0);
        }
#pragma unroll
        for (int rg = 0; rg < 4; rg++)
#pragma unroll
            for (int cg = 0; cg < 4; cg++)
                acc[rg][cg] = __builtin_amdgcn_mfma_f32_16x16x32_bf16(a[rg], b[cg], acc[rg][cg], 0, 0, 0);
    }

#pragma unroll
    for (int rg = 0; rg < 4; rg++)
#pragma unroll
        for (int cg = 0; cg < 4; cg++) {
            int col = n0 + qc + cg * 16 + l15;
            int rowb = m0 + qr + rg * 16 + quad * 4;
#pragma unroll
            for (int r = 0; r < 4; r++)
                Pn[(size_t)(rowb + r) * 512 + col] = f2b(acc[rg][cg][r]);
        }
}

// ---------------------------------------------------------------------------
// Streaming gather + layer-1: no barriers, tiny LDS, 32 waves/CU.
// Block = 256 threads = 32 edges x 16 chunks (2 edges/thread for ILP).
// Writes h1 bf16 pre-XOR-swizzled so k_gemm can async-copy linearly.
__global__ __launch_bounds__(256) void k_gather(
    const ushort* __restrict__ Pn, const int* __restrict__ sendS,
    const int* __restrict__ recS, const float* __restrict__ distS,
    const float* __restrict__ wd, const float* __restrict__ bb1,
    int p, int e_base, ushort* __restrict__ H1)
{
    const int tid = threadIdx.x;
    const int el = tid >> 4, c = tid & 15;
    const int i0 = e_base + blockIdx.x * 32 + el;

    float4 wv0 = *(const float4*)(wd + c * 8);
    float4 wv1 = *(const float4*)(wd + c * 8 + 4);
    float4 bv0 = *(const float4*)(bb1 + c * 8);
    float4 bv1 = *(const float4*)(bb1 + c * 8 + 4);
    float wva[8] = { wv0.x, wv0.y, wv0.z, wv0.w, wv1.x, wv1.y, wv1.z, wv1.w };
    float bva[8] = { bv0.x, bv0.y, bv0.z, bv0.w, bv1.x, bv1.y, bv1.z, bv1.w };

#pragma unroll
    for (int half = 0; half < 2; half++) {
        int i = i0 + half * 16;                      // i & 15 == el
        int s = sendS[i], r = recS[i];
        float d = distS[i];
        uint4 us = *(const uint4*)(Pn + (size_t)s * 512 + p * 256 + c * 8);
        uint4 ur = *(const uint4*)(Pn + (size_t)r * 512 + p * 256 + 128 + c * 8);
        const ushort* pus = (const ushort*)&us;
        const ushort* pur = (const ushort*)&ur;
        ushort res[8];
#pragma unroll
        for (int j = 0; j < 8; j++) {
            float v = b2f(pus[j]) + b2f(pur[j]) + d * wva[j] + bva[j];
            v = p ? tanh_f(v) : silu_f(v);
            res[j] = f2b(v);
        }
        *(uint4*)(H1 + (size_t)(i - e_base) * 128 + ((c ^ el) * 8)) = *(const uint4*)res;
    }
}

// ---------------------------------------------------------------------------
// Layer-2 GEMM + segment reduce over rec-sorted tiles.  H1 tile is contiguous:
// async global_load_lds copy (issued first, latency overlapped with meta/scan).
__global__ __launch_bounds__(256, 4) void k_gemm(
    const ushort* __restrict__ H1, const int* __restrict__ recS,
    const int* __restrict__ startA, const int* __restrict__ cntA,
    const float* __restrict__ x, const float* __restrict__ pe,
    const ushort* __restrict__ Wt, const float* __restrict__ bb2,
    int p, int e_base, float* __restrict__ out)
{
    __shared__ __align__(16) ushort sA[TE * 128];   // swizzled h1, then msg tile
    __shared__ int sRec[TE];
    __shared__ int sFlag[TE];
    __shared__ int sSegStart[TE + 1];

    const int tid = threadIdx.x;
    const int wave = tid >> 6, lane = tid & 63;
    const int l15 = lane & 15, quad = lane >> 4;
    const int t0 = blockIdx.x * TE;                 // tile offset within chunk

    // phase 0: async tile copy H1 -> sA (32 KB, 32 instrs, linear)
    const ushort* src = H1 + (size_t)t0 * 128;
#pragma unroll
    for (int t = 0; t < 8; t++) {
        int q = wave * 8 + t;                       // 0..31, covers rows q*4..q*4+3
        const ushort* gp = src + (size_t)(q * 4 + quad) * 128 + l15 * 8;
        gload_lds16(gp, &sA[q * 512]);
    }

    // meta while copy is in flight
    if (tid < TE) sRec[tid] = recS[e_base + t0 + tid];
    __syncthreads();
    if (tid < TE) sFlag[tid] = (tid == 0) || (sRec[tid] != sRec[tid - 1]);
    __syncthreads();
    for (int off = 1; off < TE; off <<= 1) {
        int v = (tid < TE && tid >= off) ? sFlag[tid - off] : 0;
        __syncthreads();
        if (tid < TE) sFlag[tid] += v;
        __syncthreads();
    }
    if (tid < TE && (tid == 0 || sFlag[tid] != sFlag[tid - 1]))
        sSegStart[sFlag[tid] - 1] = tid;
    if (tid == 0) sSegStart[sFlag[TE - 1]] = TE;
    __syncthreads();
    const int nSeg = sFlag[TE - 1];

    // MFMA layer 2: A from swizzled sA, B from global (L1-resident 32 KB)
    f32x4 acc[2][8];
#pragma unroll
    for (int rg = 0; rg < 2; rg++)
#pragma unroll
        for (int cg = 0; cg < 8; cg++) acc[rg][cg] = (f32x4){0.f, 0.f, 0.f, 0.f};

#pragma unroll
    for (int s4 = 0; s4 < 4; s4++) {
        int cidx = s4 * 4 + quad;
        int row0 = wave * 32 + l15;                 // row & 15 == l15
        bf16x8 a0 = *(const bf16x8*)&sA[row0 * 128 + ((cidx ^ l15) * 8)];
        bf16x8 a1 = *(const bf16x8*)&sA[(row0 + 16) * 128 + ((cidx ^ l15) * 8)];
        int k0 = cidx * 8;
#pragma unroll
        for (int cg = 0; cg < 8; cg++) {
            bf16x8 b = *(const bf16x8*)(Wt + (cg * 16 + l15) * HDIM + k0);
            acc[0][cg] = __builtin_amdgcn_mfma_f32_16x16x32_bf16(a0, b, acc[0][cg], 0, 0, 0);
            acc[1][cg] = __builtin_amdgcn_mfma_f32_16x16x32_bf16(a1, b, acc[1][cg], 0, 0, 0);
        }
    }
    __syncthreads();   // all h1 reads done before msg overwrite

    // bias + activation, msg tile into sA (plain layout)
#pragma unroll
    for (int rg = 0; rg < 2; rg++) {
        int rowb = wave * 32 + rg * 16 + quad * 4;
#pragma unroll
        for (int cg = 0; cg < 8; cg++) {
            int col = cg * 16 + l15;
            float bias = bb2[col];
#pragma unroll
            for (int r = 0; r < 4; r++) {
                float v = acc[rg][cg][r] + bias;
                v = p ? tanh_f(v) : silu_f(v);
                sA[(rowb + r) * 128 + col] = f2b(v);
            }
        }
    }
    __syncthreads();

    // segment reduce + store/atomic
    const float* basep = p ? pe : x;
    float* outb = out + (size_t)p * N_NODES * HDIM;
    for (int task = tid; task < nSeg * 64; task += 256) {
        int seg = task >> 6, cp = task & 63;
        int r0 = sSegStart[seg], r1 = sSegStart[seg + 1];
        float a0 = 0.f, a1 = 0.f;
        for (int rr = r0; rr < r1; rr++) {
            unsigned int u = *(const unsigned int*)&sA[rr * 128 + cp * 2];
            a0 += b2f((ushort)(u & 0xffffu));
            a1 += b2f((ushort)(u >> 16));
        }
        int n = sRec[r0];
        int g0 = e_base + t0 + r0;
        bool interior = (g0 == startA[n]) && (g0 + (r1 - r0) == startA[n] + cntA[n]);
        float* op = outb + (size_t)n * HDIM + cp * 2;
        if (interior) {
            float2 bv = *(const float2*)(basep + (size_t)n * HDIM + cp * 2);
            *(float2*)op = make_float2(bv.x + a0, bv.y + a1);
        } else {
            atomicAdd(op, a0);
            atomicAdd(op + 1, a1);
        }
    }
}

// ---------------------------------------------------------------------------
extern "C" void kernel_launch(void* const* d_in, const int* in_sizes, int n_in,
                              void* d_out, int out_size, void* d_ws, size_t ws_size,
                              hipStream_t stream) {
    const float* x   = (const float*)d_in[0];
    const float* pos = (const float*)d_in[1];
    const float* pe  = (const float*)d_in[2];
    const int* eidx  = (const int*)d_in[3];
    const float* W1  = (const float*)d_in[4];
    const float* b1  = (const float*)d_in[5];
    const float* W2  = (const float*)d_in[6];
    const float* b2  = (const float*)d_in[7];
    const float* Wp1 = (const float*)d_in[8];
    const float* bp1 = (const float*)d_in[9];
    const float* Wp2 = (const float*)d_in[10];
    const float* bp2 = (const float*)d_in[11];
    float* out = (float*)d_out;

    // workspace carve-up
    char* w = (char*)d_ws;
    size_t off = 0;
    ushort* Xc   = (ushort*)(w + off); off += (size_t)MPAD * 256 * 2;   // 25.6 MB
    ushort* Pn   = (ushort*)(w + off); off += (size_t)MPAD * 512 * 2;   // 51.2 MB
    ushort* WcT  = (ushort*)(w + off); off += 512 * 256 * 2;
    ushort* W2t  = (ushort*)(w + off); off += 32768;
    ushort* Wp2t = (ushort*)(w + off); off += 32768;
    float*  w1d  = (float*)(w + off);  off += 2048;
    float*  wp1d = (float*)(w + off);  off += 2048;
    int* cnt     = (int*)(w + off);    off += 200704;                   // 50176*4
    int* startA  = (int*)(w + off);    off += 200704;
    int* cursor  = (int*)(w + off);    off += 200704;
    int* locs    = (int*)(w + off);    off += 200704;
    int* sums    = (int*)(w + off);    off += 512;
    int* sendS   = (int*)(w + off);    off += (size_t)NE * 4;
    int* recS    = (int*)(w + off);    off += (size_t)NE * 4;
    float* distS = (float*)(w + off);  off += (size_t)NE * 4;
    ushort* H1   = (ushort*)(w + off);                                  // rest

    // chunk edges so H1 fits remaining scratch (256 B per edge per path)
    size_t cap = (ws_size > off) ? (ws_size - off) : 0;
    int chunk = (int)(cap / 256);
    chunk -= chunk % TE;
    if (chunk > NE) chunk = NE;
    if (chunk < TE) chunk = TE;   // assume scratch is at least this big

    // sort edges by receiver (+ dist/send/rec extraction)
    hipMemsetAsync(cnt, 0, (N_NODES + 1) * sizeof(int), stream);
    k_hist<<<(NE + 255) / 256, 256, 0, stream>>>(eidx, cnt);
    k_scan1<<<SCAN_NB, SCAN_BS, 0, stream>>>(cnt, locs, sums);
    k_scan2<<<1, 128, 0, stream>>>(sums);
    k_scan3<<<SCAN_NB, SCAN_BS, 0, stream>>>(cnt, locs, sums, startA, cursor);
    k_place<<<(NE + 255) / 256, 256, 0, stream>>>(eidx, pos, cursor, sendS, recS, distS);

    // prep (fused Xc build + out baseline init)
    k_prep_w<<<769, 256, 0, stream>>>(W1, Wp1, W2, Wp2, WcT, W2t, Wp2t, w1d, wp1d);
    k_prep_nodes<<<MPAD / 4, 256, 0, stream>>>((const float4*)x, (const float4*)pe,
                                               Xc, (float4*)out);

    // node-level GEMM: Pn = Xc @ Wc
    dim3 ggrid(4, MPAD / 128);
    k_node_gemm<<<ggrid, 256, 0, stream>>>(Xc, WcT, Pn);

    // edge pipeline: streaming gather+layer1, then tiled layer2+reduce
    for (int e_base = 0; e_base < NE; e_base += chunk) {
        int ce = NE - e_base; if (ce > chunk) ce = chunk;
        for (int p = 0; p < 2; p++) {
            k_gather<<<ce / 32, 256, 0, stream>>>(Pn, sendS, recS, distS,
                                                  p ? wp1d : w1d, p ? bp1 : b1,
                                                  p, e_base, H1);
            k_gemm<<<ce / TE, 256, 0, stream>>>(H1, recS, startA, cnt, x, pe,
                                                p ? Wp2t : W2t, p ? bp2 : b2,
                                                p, e_base, out);
        }
    }
}